// Round 1
// baseline (657.811 us; speedup 1.0000x reference)
//
#include <hip/hip_runtime.h>
#include <math.h>

// STRNN: B=16, S=128, D=64, K=64, H=128, NSLOT+1=97 slots.
//
// Pipeline (all f32):
//  ws memset: XC + histogram counters
//  k_hist      : count valid (b,i,j) triples per t-slot and per d-slot
//  k_scan      : exclusive scan -> bucket offsets + cursors (both arrays in one block)
//  k_scatter_t : scatter packed entries into t-sorted order
//  k_phaseA    : per t-bucket GEMM  xt = x[b,j] @ Tw[t]   (Tw in LDS) -> XT[entry][64]
//  k_scatter_d : re-scatter entry refs into d-sorted order
//  k_phaseB    : per d-bucket GEMM  XC[b,i,:] += xt @ Dw[d] (Dw in LDS, atomicAdd)
//  k_recur     : h = sigmoid(XC[b,i] + h@Wh), 16 blocks (one per b), Wh in LDS
//
// ws requirement: ~36 MB.

#define B_ 16
#define S_ 128
#define D_ 64
#define K_ 64
#define H_ 128
#define NS 97
#define MAXE 132096  // B * S*(S+1)/2  (upper bound on valid triples)

// u32-index offsets into ws
#define XC_OFF 0                 // f32 [2048][128] = 262144
#define CNT_T  262144            // u32 [97]
#define CNT_D  (CNT_T + 97)
#define OFF_T  (CNT_D + 97)      // u32 [98] (last = total)
#define OFF_D  (OFF_T + 98)
#define CUR_T  (OFF_D + 98)
#define CUR_D  (CUR_T + 97)
#define ENT_T  (CNT_T + 640)     // u32 [MAXE] packed: b|i<<4|j<<11|t<<18|d<<25
#define ENT_D  (ENT_T + MAXE)    // u32 [MAXE] packed: pos<<11 | (b<<7|i)
#define XT_OFF (ENT_D + MAXE)    // f32 [MAXE][64]

__global__ void k_hist(const int* tc, const int* dc, const int* mk, unsigned* wsi) {
    int bi = blockIdx.x;         // b*128 + i
    int j  = threadIdx.x;
    int i  = bi & 127;
    int idx = bi * S_ + j;
    if (j <= i && mk[idx] != 0) {
        atomicAdd(&wsi[CNT_T + tc[idx]], 1u);
        atomicAdd(&wsi[CNT_D + dc[idx]], 1u);
    }
}

__global__ void k_scan(unsigned* wsi) {
    __shared__ unsigned s[256];
    int tid  = threadIdx.x;
    int lane = tid & 127;
    int arr  = tid >> 7;  // 0 = t-array, 1 = d-array
    unsigned cbase = arr ? CNT_D : CNT_T;
    unsigned v = (lane < NS) ? wsi[cbase + lane] : 0u;
    unsigned orig = v;
    s[tid] = v;
    __syncthreads();
    for (int o = 1; o < 128; o <<= 1) {
        unsigned add = (lane >= o) ? s[tid - o] : 0u;
        __syncthreads();
        s[tid] += add;
        __syncthreads();
    }
    unsigned excl = s[tid] - orig;
    unsigned obase = arr ? OFF_D : OFF_T;
    unsigned ubase = arr ? CUR_D : CUR_T;
    if (lane < NS) { wsi[obase + lane] = excl; wsi[ubase + lane] = excl; }
    if (lane == 0) { wsi[obase + NS] = s[arr * 128 + 96]; }  // total
}

__global__ void k_scatter_t(const int* tc, const int* dc, const int* mk, unsigned* wsi) {
    int bi = blockIdx.x;
    int j  = threadIdx.x;
    int i  = bi & 127;
    int b  = bi >> 7;
    int idx = bi * S_ + j;
    if (j <= i && mk[idx] != 0) {
        unsigned t = (unsigned)tc[idx], d = (unsigned)dc[idx];
        unsigned pos = atomicAdd(&wsi[CUR_T + t], 1u);
        wsi[ENT_T + pos] = (unsigned)b | ((unsigned)i << 4) | ((unsigned)j << 11)
                         | (t << 18) | (d << 25);
    }
}

// phase A: xt[entry][kk] = sum_dd x[b,j][dd] * Tw[t][dd][kk]
__global__ __launch_bounds__(256) void k_phaseA(const float* __restrict__ x,
                                                const float* __restrict__ tw,
                                                unsigned* wsi, float* wsf) {
    int t = blockIdx.x, c = blockIdx.y;
    int rows = (int)wsi[CNT_T + t] - c * 128;
    if (rows <= 0) return;
    if (rows > 128) rows = 128;
    unsigned base = wsi[OFF_T + t] + c * 128;

    __shared__ float stw[4096];     // Tw[t] row-major [dd][kk]
    __shared__ float sx[8192];      // x rows, XOR-swizzled in 4-float units
    __shared__ unsigned ent[128];
    int tid = threadIdx.x;

    const float4* twg = (const float4*)(tw + t * 4096);
    float4* stw4 = (float4*)stw;
    #pragma unroll
    for (int q = 0; q < 4; q++) stw4[q * 256 + tid] = twg[q * 256 + tid];
    if (tid < 128) ent[tid] = (tid < rows) ? wsi[ENT_T + base + tid] : 0u;
    __syncthreads();

    int lane16 = tid & 15, rquot = tid >> 4;
    #pragma unroll
    for (int p = 0; p < 8; p++) {
        int r = p * 16 + rquot;
        float4 v = make_float4(0.f, 0.f, 0.f, 0.f);
        if (r < rows) {
            unsigned e = ent[r];
            int b = e & 15, j = (e >> 11) & 127;
            v = *(const float4*)(x + (b * S_ + j) * D_ + lane16 * 4);
        }
        int col4 = lane16 ^ (r & 15);
        float* dst = &sx[r * 64 + col4 * 4];
        dst[0] = v.x; dst[1] = v.y; dst[2] = v.z; dst[3] = v.w;
    }
    __syncthreads();

    int rgrp = tid & 15, cgrp = tid >> 4;   // 8 rows (rgrp+16i) x 4 cols (cgrp*4..)
    float4 acc[8];
    #pragma unroll
    for (int i = 0; i < 8; i++) acc[i] = make_float4(0.f, 0.f, 0.f, 0.f);
    #pragma unroll 4
    for (int dd = 0; dd < 64; dd++) {
        float4 w = stw4[dd * 16 + cgrp];
        int s_idx = (((dd >> 2) ^ rgrp) << 2) + (dd & 3);
        #pragma unroll
        for (int i = 0; i < 8; i++) {
            float a = sx[(rgrp + 16 * i) * 64 + s_idx];
            acc[i].x += a * w.x; acc[i].y += a * w.y;
            acc[i].z += a * w.z; acc[i].w += a * w.w;
        }
    }
    float* XT = wsf + XT_OFF;
    #pragma unroll
    for (int i = 0; i < 8; i++) {
        int r = rgrp + 16 * i;
        if (r < rows) *(float4*)(XT + (size_t)(base + r) * 64 + cgrp * 4) = acc[i];
    }
}

__global__ void k_scatter_d(unsigned* wsi) {
    unsigned gid = blockIdx.x * 256 + threadIdx.x;
    unsigned total = wsi[OFF_T + NS];
    if (gid < total) {
        unsigned e = wsi[ENT_T + gid];
        unsigned d = e >> 25;
        unsigned dst = ((e & 15u) << 7) | ((e >> 4) & 127u);  // b*128+i
        unsigned pos = atomicAdd(&wsi[CUR_D + d], 1u);
        wsi[ENT_D + pos] = (gid << 11) | dst;
    }
}

// phase B: XC[dst][hh] += sum_kk xt[entry][kk] * Dw[d][kk][hh]
__global__ __launch_bounds__(256) void k_phaseB(const float* __restrict__ dw,
                                                unsigned* wsi, float* wsf) {
    int d = blockIdx.x, c = blockIdx.y;
    int rows = (int)wsi[CNT_D + d] - c * 128;
    if (rows <= 0) return;
    if (rows > 128) rows = 128;
    unsigned base = wsi[OFF_D + d] + c * 128;

    __shared__ float sdw[8192];     // Dw[d] row-major [kk][hh]
    __shared__ float sx[8192];      // xt rows, swizzled
    __shared__ unsigned ent[128];
    int tid = threadIdx.x;

    const float4* dwg = (const float4*)(dw + (size_t)d * 8192);
    float4* sdw4 = (float4*)sdw;
    #pragma unroll
    for (int q = 0; q < 8; q++) sdw4[q * 256 + tid] = dwg[q * 256 + tid];
    if (tid < 128) ent[tid] = (tid < rows) ? wsi[ENT_D + base + tid] : 0u;
    __syncthreads();

    const float* XT = wsf + XT_OFF;
    int lane16 = tid & 15, rquot = tid >> 4;
    #pragma unroll
    for (int p = 0; p < 8; p++) {
        int r = p * 16 + rquot;
        float4 v = make_float4(0.f, 0.f, 0.f, 0.f);
        if (r < rows) {
            unsigned pos = ent[r] >> 11;
            v = *(const float4*)(XT + (size_t)pos * 64 + lane16 * 4);
        }
        int col4 = lane16 ^ (r & 15);
        float* dst2 = &sx[r * 64 + col4 * 4];
        dst2[0] = v.x; dst2[1] = v.y; dst2[2] = v.z; dst2[3] = v.w;
    }
    __syncthreads();

    int rgrp = tid & 15, cgrp = tid >> 4;   // 8 rows x 8 cols (cgrp*8..)
    float4 a0[8], a1[8];
    #pragma unroll
    for (int i = 0; i < 8; i++) {
        a0[i] = make_float4(0.f, 0.f, 0.f, 0.f);
        a1[i] = make_float4(0.f, 0.f, 0.f, 0.f);
    }
    #pragma unroll 2
    for (int kk = 0; kk < 64; kk++) {
        float4 w0 = sdw4[kk * 32 + cgrp * 2];
        float4 w1 = sdw4[kk * 32 + cgrp * 2 + 1];
        int s_idx = (((kk >> 2) ^ rgrp) << 2) + (kk & 3);
        #pragma unroll
        for (int i = 0; i < 8; i++) {
            float a = sx[(rgrp + 16 * i) * 64 + s_idx];
            a0[i].x += a * w0.x; a0[i].y += a * w0.y; a0[i].z += a * w0.z; a0[i].w += a * w0.w;
            a1[i].x += a * w1.x; a1[i].y += a * w1.y; a1[i].z += a * w1.z; a1[i].w += a * w1.w;
        }
    }
    float* XC = wsf + XC_OFF;
    #pragma unroll
    for (int i = 0; i < 8; i++) {
        int r = rgrp + 16 * i;
        if (r < rows) {
            unsigned dst = ent[r] & 2047u;
            float* p = XC + (size_t)dst * 128 + cgrp * 8;
            atomicAdd(p + 0, a0[i].x); atomicAdd(p + 1, a0[i].y);
            atomicAdd(p + 2, a0[i].z); atomicAdd(p + 3, a0[i].w);
            atomicAdd(p + 4, a1[i].x); atomicAdd(p + 5, a1[i].y);
            atomicAdd(p + 6, a1[i].z); atomicAdd(p + 7, a1[i].w);
        }
    }
}

// recurrence: h_new = sigmoid(XC[b,i] + h @ Wh); one block per batch b
__global__ __launch_bounds__(512) void k_recur(const float* __restrict__ hw,
                                               const float* __restrict__ wsf,
                                               float* __restrict__ out) {
    int b = blockIdx.x;
    __shared__ float swh[16384];    // Wh row-major [k][h']
    __shared__ float sh[128];
    __shared__ float part[4][128];
    int tid = threadIdx.x;

    float4* swh4 = (float4*)swh;
    const float4* hwg = (const float4*)hw;
    #pragma unroll
    for (int q = 0; q < 8; q++) swh4[q * 512 + tid] = hwg[q * 512 + tid];
    if (tid < 128) sh[tid] = 0.f;
    __syncthreads();

    int hp = tid & 127, seg = tid >> 7;   // 4 segs x 32 k each
    int k0 = seg * 32;
    for (int i = 0; i < 128; i++) {
        float acc0 = (seg == 0) ? wsf[XC_OFF + ((size_t)(b * 128 + i)) * 128 + hp] : 0.f;
        float acc1 = 0.f, acc2 = 0.f, acc3 = 0.f;
        #pragma unroll 8
        for (int k = k0; k < k0 + 32; k += 4) {
            acc0 += sh[k + 0] * swh[(k + 0) * 128 + hp];
            acc1 += sh[k + 1] * swh[(k + 1) * 128 + hp];
            acc2 += sh[k + 2] * swh[(k + 2) * 128 + hp];
            acc3 += sh[k + 3] * swh[(k + 3) * 128 + hp];
        }
        part[seg][hp] = (acc0 + acc1) + (acc2 + acc3);
        __syncthreads();
        if (tid < 128) {
            float v = (part[0][hp] + part[1][hp]) + (part[2][hp] + part[3][hp]);
            v = 1.f / (1.f + expf(-v));
            sh[hp] = v;
            out[((size_t)(b * 128 + i)) * 128 + hp] = v;
        }
        __syncthreads();
    }
    if (tid < 128) out[(size_t)B_ * S_ * H_ + b * 128 + hp] = sh[hp];
}

extern "C" void kernel_launch(void* const* d_in, const int* in_sizes, int n_in,
                              void* d_out, int out_size, void* d_ws, size_t ws_size,
                              hipStream_t stream) {
    const float* x  = (const float*)d_in[0];
    const int*   tc = (const int*)d_in[1];
    const int*   dc = (const int*)d_in[2];
    const int*   mk = (const int*)d_in[3];   // bool masks, assumed pushed as int32
    const float* tw = (const float*)d_in[4];
    const float* dw = (const float*)d_in[5];
    const float* hw = (const float*)d_in[6];
    float*    out = (float*)d_out;
    float*    wsf = (float*)d_ws;
    unsigned* wsi = (unsigned*)d_ws;

    // zero XC + counters (offs/cur are overwritten by k_scan; entries/XT fully rewritten)
    hipMemsetAsync(d_ws, 0, (size_t)ENT_T * 4, stream);

    k_hist<<<dim3(2048), dim3(128), 0, stream>>>(tc, dc, mk, wsi);
    k_scan<<<dim3(1), dim3(256), 0, stream>>>(wsi);
    k_scatter_t<<<dim3(2048), dim3(128), 0, stream>>>(tc, dc, mk, wsi);
    k_phaseA<<<dim3(NS, 16), dim3(256), 0, stream>>>(x, tw, wsi, wsf);
    k_scatter_d<<<dim3(516), dim3(256), 0, stream>>>(wsi);
    k_phaseB<<<dim3(NS, 16), dim3(256), 0, stream>>>(dw, wsi, wsf);
    k_recur<<<dim3(16), dim3(512), 0, stream>>>(hw, wsf, out);
}

// Round 2
// 425.247 us; speedup vs baseline: 1.5469x; 1.5469x over previous
//
#include <hip/hip_runtime.h>
#include <math.h>

// STRNN: B=16, S=128, D=64, K=64, H=128, NSLOT+1=97 slots.
//
// Pipeline (all f32):
//  memset counters
//  k_hist      : count valid (b,i,j) triples per t-slot, d-slot, and per (b,i) dst
//  k_scan      : exclusive scan of t/d counts -> bucket offsets + cursors
//  k_scan_b    : exclusive scan of dst counts (2048)
//  k_scatter_t : scatter packed entries into t-sorted order
//  k_phaseA    : per t-bucket GEMM  xt = x[b,j] @ Tw[t]   (Tw in LDS) -> XT[entry][64]
//  k_scatter_d : re-scatter entry refs into d-sorted order; assign dst-sorted Y slots
//  k_phaseB    : per d-bucket GEMM  y = xt @ Dw[d] (Dw in LDS) -> Y[dstpos][128]
//                (no atomics; falls back to atomicAdd-into-XC if ws too small)
//  k_reduce    : XC[b,i,:] = sum of its contiguous Y rows
//  k_recur     : h = sigmoid(XC[b,i] + h@Wh), 16 blocks (one per b), Wh in LDS
//
// ws requirement: ~104 MB for the atomic-free path (guarded at launch).

#define B_ 16
#define S_ 128
#define D_ 64
#define K_ 64
#define H_ 128
#define NS 97
#define MAXE 132096  // B * S*(S+1)/2  (upper bound on valid triples)

// u32/f32-index offsets into ws
#define XC_OFF 0                 // f32 [2048][128]
#define CNT_T  262144            // u32 [97]
#define CNT_D  (CNT_T + 97)      // u32 [97]
#define CNT_B  (CNT_D + 97)      // u32 [2048]
#define CUR_T  (CNT_B + 2048)    // u32 [97]
#define CUR_D  (CUR_T + 97)      // u32 [97]
#define CUR_B  (CUR_D + 97)      // u32 [2048]
#define OFF_T  (CUR_B + 2048)    // u32 [98] (last = total)
#define OFF_D  (OFF_T + 98)      // u32 [98]
#define OFF_B  (OFF_D + 98)      // u32 [2049]
#define ENT_T  270336            // u32 [MAXE] packed: b|i<<4|j<<11|t<<18|d<<25
#define ENT_DX (ENT_T + MAXE)    // u32 [MAXE] xt-row index (t-sorted pos)
#define ENT_DP (ENT_DX + MAXE)   // u32 [MAXE] Y-row (dst-sorted pos)  [or dst in fallback]
#define XT_OFF (ENT_DP + MAXE)   // f32 [MAXE][64]
#define Y_OFF  (XT_OFF + MAXE * 64)            // f32 [MAXE][128]
#define NEED_BYTES ((size_t)(Y_OFF + (size_t)MAXE * 128) * 4)

__global__ void k_hist(const int* tc, const int* dc, const int* mk, unsigned* wsi) {
    __shared__ unsigned cnt;
    int bi = blockIdx.x;         // b*128 + i
    int j  = threadIdx.x;
    int i  = bi & 127;
    int idx = bi * S_ + j;
    if (j == 0) cnt = 0;
    __syncthreads();
    if (j <= i && mk[idx] != 0) {
        atomicAdd(&wsi[CNT_T + tc[idx]], 1u);
        atomicAdd(&wsi[CNT_D + dc[idx]], 1u);
        atomicAdd(&cnt, 1u);
    }
    __syncthreads();
    if (j == 0) wsi[CNT_B + bi] = cnt;
}

__global__ void k_scan(unsigned* wsi) {
    __shared__ unsigned s[256];
    int tid  = threadIdx.x;
    int lane = tid & 127;
    int arr  = tid >> 7;  // 0 = t-array, 1 = d-array
    unsigned cbase = arr ? CNT_D : CNT_T;
    unsigned v = (lane < NS) ? wsi[cbase + lane] : 0u;
    unsigned orig = v;
    s[tid] = v;
    __syncthreads();
    for (int o = 1; o < 128; o <<= 1) {
        unsigned add = (lane >= o) ? s[tid - o] : 0u;
        __syncthreads();
        s[tid] += add;
        __syncthreads();
    }
    unsigned excl = s[tid] - orig;
    unsigned obase = arr ? OFF_D : OFF_T;
    unsigned ubase = arr ? CUR_D : CUR_T;
    if (lane < NS) { wsi[obase + lane] = excl; wsi[ubase + lane] = excl; }
    if (lane == 0) { wsi[obase + NS] = s[arr * 128 + 96]; }  // total
}

// scan of the 2048 per-(b,i) counts -> OFF_B / CUR_B
__global__ void k_scan_b(unsigned* wsi) {
    __shared__ unsigned s[256];
    int tid = threadIdx.x;
    unsigned v[8], sum = 0;
    #pragma unroll
    for (int u = 0; u < 8; u++) { v[u] = wsi[CNT_B + tid * 8 + u]; sum += v[u]; }
    s[tid] = sum;
    __syncthreads();
    for (int o = 1; o < 256; o <<= 1) {
        unsigned add = (tid >= o) ? s[tid - o] : 0u;
        __syncthreads();
        s[tid] += add;
        __syncthreads();
    }
    unsigned run = s[tid] - sum;
    #pragma unroll
    for (int u = 0; u < 8; u++) {
        wsi[OFF_B + tid * 8 + u] = run;
        wsi[CUR_B + tid * 8 + u] = run;
        run += v[u];
    }
    if (tid == 255) wsi[OFF_B + 2048] = run;
}

__global__ void k_scatter_t(const int* tc, const int* dc, const int* mk, unsigned* wsi) {
    int bi = blockIdx.x;
    int j  = threadIdx.x;
    int i  = bi & 127;
    int b  = bi >> 7;
    int idx = bi * S_ + j;
    if (j <= i && mk[idx] != 0) {
        unsigned t = (unsigned)tc[idx], d = (unsigned)dc[idx];
        unsigned pos = atomicAdd(&wsi[CUR_T + t], 1u);
        wsi[ENT_T + pos] = (unsigned)b | ((unsigned)i << 4) | ((unsigned)j << 11)
                         | (t << 18) | (d << 25);
    }
}

// phase A: xt[entry][kk] = sum_dd x[b,j][dd] * Tw[t][dd][kk]
__global__ __launch_bounds__(256) void k_phaseA(const float* __restrict__ x,
                                                const float* __restrict__ tw,
                                                unsigned* wsi, float* wsf) {
    int t = blockIdx.x, c = blockIdx.y;
    int rows = (int)wsi[CNT_T + t] - c * 128;
    if (rows <= 0) return;
    if (rows > 128) rows = 128;
    unsigned base = wsi[OFF_T + t] + c * 128;

    __shared__ float stw[4096];     // Tw[t] row-major [dd][kk]
    __shared__ float sx[8192];      // x rows, XOR-swizzled in 4-float units
    __shared__ unsigned ent[128];
    int tid = threadIdx.x;

    const float4* twg = (const float4*)(tw + t * 4096);
    float4* stw4 = (float4*)stw;
    #pragma unroll
    for (int q = 0; q < 4; q++) stw4[q * 256 + tid] = twg[q * 256 + tid];
    if (tid < 128) ent[tid] = (tid < rows) ? wsi[ENT_T + base + tid] : 0u;
    __syncthreads();

    int lane16 = tid & 15, rquot = tid >> 4;
    #pragma unroll
    for (int p = 0; p < 8; p++) {
        int r = p * 16 + rquot;
        float4 v = make_float4(0.f, 0.f, 0.f, 0.f);
        if (r < rows) {
            unsigned e = ent[r];
            int b = e & 15, j = (e >> 11) & 127;
            v = *(const float4*)(x + (b * S_ + j) * D_ + lane16 * 4);
        }
        int col4 = lane16 ^ (r & 15);
        float* dst = &sx[r * 64 + col4 * 4];
        dst[0] = v.x; dst[1] = v.y; dst[2] = v.z; dst[3] = v.w;
    }
    __syncthreads();

    int rgrp = tid & 15, cgrp = tid >> 4;   // 8 rows (rgrp+16i) x 4 cols (cgrp*4..)
    float4 acc[8];
    #pragma unroll
    for (int i = 0; i < 8; i++) acc[i] = make_float4(0.f, 0.f, 0.f, 0.f);
    #pragma unroll 4
    for (int dd = 0; dd < 64; dd++) {
        float4 w = stw4[dd * 16 + cgrp];
        int s_idx = (((dd >> 2) ^ rgrp) << 2) + (dd & 3);
        #pragma unroll
        for (int i = 0; i < 8; i++) {
            float a = sx[(rgrp + 16 * i) * 64 + s_idx];
            acc[i].x += a * w.x; acc[i].y += a * w.y;
            acc[i].z += a * w.z; acc[i].w += a * w.w;
        }
    }
    float* XT = wsf + XT_OFF;
    #pragma unroll
    for (int i = 0; i < 8; i++) {
        int r = rgrp + 16 * i;
        if (r < rows) *(float4*)(XT + (size_t)(base + r) * 64 + cgrp * 4) = acc[i];
    }
}

__global__ void k_scatter_d(unsigned* wsi, int useY) {
    unsigned gid = blockIdx.x * 256 + threadIdx.x;
    unsigned total = wsi[OFF_T + NS];
    if (gid < total) {
        unsigned e = wsi[ENT_T + gid];
        unsigned d = e >> 25;
        unsigned dst = ((e & 15u) << 7) | ((e >> 4) & 127u);  // b*128+i
        unsigned pos = atomicAdd(&wsi[CUR_D + d], 1u);
        wsi[ENT_DX + pos] = gid;
        wsi[ENT_DP + pos] = useY ? atomicAdd(&wsi[CUR_B + dst], 1u) : dst;
    }
}

// phase B: y[hh] = sum_kk xt[entry][kk] * Dw[d][kk][hh]; write to Y[dstpos] (or atomic XC)
__global__ __launch_bounds__(256) void k_phaseB(const float* __restrict__ dw,
                                                unsigned* wsi, float* wsf, int useY) {
    int d = blockIdx.x, c = blockIdx.y;
    int rows = (int)wsi[CNT_D + d] - c * 128;
    if (rows <= 0) return;
    if (rows > 128) rows = 128;
    unsigned base = wsi[OFF_D + d] + c * 128;

    __shared__ float sdw[8192];     // Dw[d] row-major [kk][hh]
    __shared__ float sx[8192];      // xt rows, swizzled
    __shared__ unsigned entx[128];
    __shared__ unsigned entp[128];
    int tid = threadIdx.x;

    const float4* dwg = (const float4*)(dw + (size_t)d * 8192);
    float4* sdw4 = (float4*)sdw;
    #pragma unroll
    for (int q = 0; q < 8; q++) sdw4[q * 256 + tid] = dwg[q * 256 + tid];
    if (tid < 128) {
        entx[tid] = (tid < rows) ? wsi[ENT_DX + base + tid] : 0u;
        entp[tid] = (tid < rows) ? wsi[ENT_DP + base + tid] : 0u;
    }
    __syncthreads();

    const float* XT = wsf + XT_OFF;
    int lane16 = tid & 15, rquot = tid >> 4;
    #pragma unroll
    for (int p = 0; p < 8; p++) {
        int r = p * 16 + rquot;
        float4 v = make_float4(0.f, 0.f, 0.f, 0.f);
        if (r < rows) {
            unsigned pos = entx[r];
            v = *(const float4*)(XT + (size_t)pos * 64 + lane16 * 4);
        }
        int col4 = lane16 ^ (r & 15);
        float* dst2 = &sx[r * 64 + col4 * 4];
        dst2[0] = v.x; dst2[1] = v.y; dst2[2] = v.z; dst2[3] = v.w;
    }
    __syncthreads();

    int rgrp = tid & 15, cgrp = tid >> 4;   // 8 rows x 8 cols (cgrp*8..)
    float4 a0[8], a1[8];
    #pragma unroll
    for (int i = 0; i < 8; i++) {
        a0[i] = make_float4(0.f, 0.f, 0.f, 0.f);
        a1[i] = make_float4(0.f, 0.f, 0.f, 0.f);
    }
    #pragma unroll 2
    for (int kk = 0; kk < 64; kk++) {
        float4 w0 = sdw4[kk * 32 + cgrp * 2];
        float4 w1 = sdw4[kk * 32 + cgrp * 2 + 1];
        int s_idx = (((kk >> 2) ^ rgrp) << 2) + (kk & 3);
        #pragma unroll
        for (int i = 0; i < 8; i++) {
            float a = sx[(rgrp + 16 * i) * 64 + s_idx];
            a0[i].x += a * w0.x; a0[i].y += a * w0.y; a0[i].z += a * w0.z; a0[i].w += a * w0.w;
            a1[i].x += a * w1.x; a1[i].y += a * w1.y; a1[i].z += a * w1.z; a1[i].w += a * w1.w;
        }
    }
    if (useY) {
        float* Y = wsf + Y_OFF;
        #pragma unroll
        for (int i = 0; i < 8; i++) {
            int r = rgrp + 16 * i;
            if (r < rows) {
                float* p = Y + (size_t)entp[r] * 128 + cgrp * 8;
                *(float4*)p = a0[i];
                *(float4*)(p + 4) = a1[i];
            }
        }
    } else {
        float* XC = wsf + XC_OFF;
        #pragma unroll
        for (int i = 0; i < 8; i++) {
            int r = rgrp + 16 * i;
            if (r < rows) {
                float* p = XC + (size_t)entp[r] * 128 + cgrp * 8;
                atomicAdd(p + 0, a0[i].x); atomicAdd(p + 1, a0[i].y);
                atomicAdd(p + 2, a0[i].z); atomicAdd(p + 3, a0[i].w);
                atomicAdd(p + 4, a1[i].x); atomicAdd(p + 5, a1[i].y);
                atomicAdd(p + 6, a1[i].z); atomicAdd(p + 7, a1[i].w);
            }
        }
    }
}

// XC[b,i,:] = sum of this (b,i)'s contiguous Y rows
__global__ __launch_bounds__(128) void k_reduce(unsigned* wsi, float* wsf) {
    int bi = blockIdx.x, tid = threadIdx.x;
    unsigned n = wsi[CNT_B + bi], off = wsi[OFF_B + bi];
    const float* Yp = wsf + Y_OFF + (size_t)off * 128 + tid;
    float a0 = 0.f, a1 = 0.f, a2 = 0.f, a3 = 0.f;
    unsigned e = 0;
    for (; e + 4 <= n; e += 4) {
        a0 += Yp[(size_t)e * 128];
        a1 += Yp[(size_t)(e + 1) * 128];
        a2 += Yp[(size_t)(e + 2) * 128];
        a3 += Yp[(size_t)(e + 3) * 128];
    }
    for (; e < n; e++) a0 += Yp[(size_t)e * 128];
    wsf[XC_OFF + (size_t)bi * 128 + tid] = (a0 + a1) + (a2 + a3);
}

// recurrence: h_new = sigmoid(XC[b,i] + h @ Wh); one block per batch b
__global__ __launch_bounds__(512) void k_recur(const float* __restrict__ hw,
                                               const float* __restrict__ wsf,
                                               float* __restrict__ out) {
    int b = blockIdx.x;
    __shared__ float swh[16384];    // Wh row-major [k][h']
    __shared__ float sh[128];
    __shared__ float part[4][128];
    int tid = threadIdx.x;

    float4* swh4 = (float4*)swh;
    const float4* hwg = (const float4*)hw;
    #pragma unroll
    for (int q = 0; q < 8; q++) swh4[q * 512 + tid] = hwg[q * 512 + tid];
    if (tid < 128) sh[tid] = 0.f;
    __syncthreads();

    int hp = tid & 127, seg = tid >> 7;   // 4 segs x 32 k each
    int k0 = seg * 32;
    for (int i = 0; i < 128; i++) {
        float acc0 = (seg == 0) ? wsf[XC_OFF + ((size_t)(b * 128 + i)) * 128 + hp] : 0.f;
        float acc1 = 0.f, acc2 = 0.f, acc3 = 0.f;
        #pragma unroll 8
        for (int k = k0; k < k0 + 32; k += 4) {
            acc0 += sh[k + 0] * swh[(k + 0) * 128 + hp];
            acc1 += sh[k + 1] * swh[(k + 1) * 128 + hp];
            acc2 += sh[k + 2] * swh[(k + 2) * 128 + hp];
            acc3 += sh[k + 3] * swh[(k + 3) * 128 + hp];
        }
        part[seg][hp] = (acc0 + acc1) + (acc2 + acc3);
        __syncthreads();
        if (tid < 128) {
            float v = (part[0][hp] + part[1][hp]) + (part[2][hp] + part[3][hp]);
            v = 1.f / (1.f + expf(-v));
            sh[hp] = v;
            out[((size_t)(b * 128 + i)) * 128 + hp] = v;
        }
        __syncthreads();
    }
    if (tid < 128) out[(size_t)B_ * S_ * H_ + b * 128 + hp] = sh[hp];
}

extern "C" void kernel_launch(void* const* d_in, const int* in_sizes, int n_in,
                              void* d_out, int out_size, void* d_ws, size_t ws_size,
                              hipStream_t stream) {
    const float* x  = (const float*)d_in[0];
    const int*   tc = (const int*)d_in[1];
    const int*   dc = (const int*)d_in[2];
    const int*   mk = (const int*)d_in[3];   // bool masks pushed as int32
    const float* tw = (const float*)d_in[4];
    const float* dw = (const float*)d_in[5];
    const float* hw = (const float*)d_in[6];
    float*    out = (float*)d_out;
    float*    wsf = (float*)d_ws;
    unsigned* wsi = (unsigned*)d_ws;
    char*     wsb = (char*)d_ws;

    int useY = (ws_size >= NEED_BYTES) ? 1 : 0;

    // zero counter region (CNT_T, CNT_D, CNT_B); OFF/CUR are written by the scans
    hipMemsetAsync(wsb + (size_t)CNT_T * 4, 0, (size_t)(CNT_B + 2048 - CNT_T) * 4, stream);
    if (!useY)  // fallback path accumulates into XC with atomics -> needs zeroed XC
        hipMemsetAsync(wsb, 0, (size_t)262144 * 4, stream);

    k_hist<<<dim3(2048), dim3(128), 0, stream>>>(tc, dc, mk, wsi);
    k_scan<<<dim3(1), dim3(256), 0, stream>>>(wsi);
    if (useY) k_scan_b<<<dim3(1), dim3(256), 0, stream>>>(wsi);
    k_scatter_t<<<dim3(2048), dim3(128), 0, stream>>>(tc, dc, mk, wsi);
    k_phaseA<<<dim3(NS, 16), dim3(256), 0, stream>>>(x, tw, wsi, wsf);
    k_scatter_d<<<dim3(516), dim3(256), 0, stream>>>(wsi, useY);
    k_phaseB<<<dim3(NS, 16), dim3(256), 0, stream>>>(dw, wsi, wsf, useY);
    if (useY) k_reduce<<<dim3(2048), dim3(128), 0, stream>>>(wsi, wsf);
    k_recur<<<dim3(16), dim3(512), 0, stream>>>(hw, wsf, out);
}

// Round 3
// 200.095 us; speedup vs baseline: 3.2875x; 2.1252x over previous
//
#include <hip/hip_runtime.h>
#include <math.h>

// STRNN: B=16, S=128, D=64, K=64, H=128, NSLOT+1=97 slots.
//
// Pipeline (all f32), no contended global atomics:
//  k_hist1    : per-block LDS histograms of t-slot / d-slot / per-(b,i) counts
//  k_scan_all : exclusive scans -> per-(bin,block) bases + OFF_T/OFF_D/OFF_B
//  k_scatter  : one pass; LDS cursors; emits t-sorted entries, d-sorted refs, Y slots
//  k_phaseA   : per t-bucket GEMM  xt = x[b,j] @ Tw[t]   (Tw in LDS) -> XT[tpos][64]
//  k_phaseB   : per d-bucket GEMM  y = xt @ Dw[d] (Dw in LDS) -> Y[dstpos][128]
//  k_reduce   : XC[b,i,:] = sum of its contiguous Y rows
//  k_recur    : h = sigmoid(XC[b,i] + h@Wh), 16 blocks (one per b), Wh in LDS
//
// ws requirement: ~104.3 MB for the atomic-free path (guarded; fallback = atomicAdd XC).

#define B_ 16
#define S_ 128
#define D_ 64
#define K_ 64
#define H_ 128
#define NS 97
#define MAXE 132096  // B * S*(S+1)/2  (upper bound on valid triples)

// u32/f32-index offsets into ws
#define XC_OFF 0                  // f32 [2048][128]
#define BH_T   262144             // u32 [97][256]  per-(bin,block) hist -> bases
#define BH_D   (BH_T + 24832)     // u32 [97][256]
#define CNT_T  (BH_D + 24832)     // u32 [97]
#define CNT_D  (CNT_T + 97)       // u32 [97]
#define CNT_B  (CNT_D + 97)       // u32 [2048]
#define OFF_T  (CNT_B + 2048)     // u32 [98] (last = total)
#define OFF_D  (OFF_T + 98)       // u32 [98]
#define OFF_B  (OFF_D + 98)       // u32 [2049]
#define ENT_T  316296             // u32 [MAXE] packed: b|i<<4|j<<11|t<<18|d<<25 (16B-aligned)
#define ENT_DX (ENT_T + MAXE)     // u32 [MAXE] xt-row index (t-sorted pos)
#define ENT_DP (ENT_DX + MAXE)    // u32 [MAXE] Y-row (dst-sorted pos) [or dst in fallback]
#define XT_OFF (ENT_DP + MAXE)    // f32 [MAXE][64]
#define Y_OFF  (XT_OFF + MAXE * 64)            // f32 [MAXE][128]
#define NEED_BYTES ((size_t)(Y_OFF + (size_t)MAXE * 128) * 4)

// ---- binning: 256 blocks x 1024 elements (8 full (b,i) rows per block) ----

__global__ __launch_bounds__(256) void k_hist1(const int* __restrict__ tc,
                                               const int* __restrict__ dc,
                                               const int* __restrict__ mk,
                                               unsigned* wsi) {
    __shared__ unsigned ht[NS], hd[NS], hb[8];
    int tid = threadIdx.x, blk = blockIdx.x;
    if (tid < NS) { ht[tid] = 0; hd[tid] = 0; }
    if (tid < 8) hb[tid] = 0;
    __syncthreads();
    int base = blk * 1024;
    #pragma unroll
    for (int u = 0; u < 4; u++) {
        int idx = base + tid + u * 256;
        int i = (idx >> 7) & 127, j = idx & 127;
        if (j <= i && mk[idx] != 0) {
            atomicAdd(&ht[tc[idx]], 1u);
            atomicAdd(&hd[dc[idx]], 1u);
            atomicAdd(&hb[(idx >> 7) & 7], 1u);
        }
    }
    __syncthreads();
    if (tid < NS) {
        wsi[BH_T + tid * 256 + blk] = ht[tid];
        wsi[BH_D + tid * 256 + blk] = hd[tid];
    }
    if (tid < 8) wsi[CNT_B + blk * 8 + tid] = hb[tid];
}

template <int CH>
__device__ unsigned scan_region(unsigned* in, unsigned* out, int L, unsigned* s) {
    int tid = threadIdx.x;
    unsigned loc[CH], sum = 0;
    #pragma unroll
    for (int k = 0; k < CH; k++) {
        int idx = tid * CH + k;
        loc[k] = (idx < L) ? in[idx] : 0u;
        sum += loc[k];
    }
    s[tid] = sum;
    __syncthreads();
    for (int o = 1; o < 1024; o <<= 1) {
        unsigned a = (tid >= o) ? s[tid - o] : 0u;
        __syncthreads();
        s[tid] += a;
        __syncthreads();
    }
    unsigned total = s[1023];
    unsigned run = s[tid] - sum;
    __syncthreads();
    #pragma unroll
    for (int k = 0; k < CH; k++) {
        int idx = tid * CH + k;
        if (idx < L) { out[idx] = run; run += loc[k]; }
    }
    __syncthreads();
    return total;
}

__global__ __launch_bounds__(1024) void k_scan_all(unsigned* wsi) {
    __shared__ unsigned s[1024];
    int tid = threadIdx.x;

    unsigned totT = scan_region<25>(wsi + BH_T, wsi + BH_T, NS * 256, s);
    if (tid < NS) {
        unsigned b0 = wsi[BH_T + tid * 256];
        unsigned b1 = (tid < NS - 1) ? wsi[BH_T + (tid + 1) * 256] : totT;
        wsi[OFF_T + tid] = b0;
        wsi[CNT_T + tid] = b1 - b0;
    }
    if (tid == 0) wsi[OFF_T + NS] = totT;
    __syncthreads();

    unsigned totD = scan_region<25>(wsi + BH_D, wsi + BH_D, NS * 256, s);
    if (tid < NS) {
        unsigned b0 = wsi[BH_D + tid * 256];
        unsigned b1 = (tid < NS - 1) ? wsi[BH_D + (tid + 1) * 256] : totD;
        wsi[OFF_D + tid] = b0;
        wsi[CNT_D + tid] = b1 - b0;
    }
    if (tid == 0) wsi[OFF_D + NS] = totD;
    __syncthreads();

    unsigned totB = scan_region<2>(wsi + CNT_B, wsi + OFF_B, 2048, s);
    if (tid == 0) wsi[OFF_B + 2048] = totB;
}

__global__ __launch_bounds__(256) void k_scatter(const int* __restrict__ tc,
                                                 const int* __restrict__ dc,
                                                 const int* __restrict__ mk,
                                                 unsigned* wsi, int useY) {
    __shared__ unsigned ct[NS], cd[NS], cb[8];
    int tid = threadIdx.x, blk = blockIdx.x;
    if (tid < NS) {
        ct[tid] = wsi[BH_T + tid * 256 + blk];
        cd[tid] = wsi[BH_D + tid * 256 + blk];
    }
    if (tid < 8) cb[tid] = wsi[OFF_B + blk * 8 + tid];
    __syncthreads();
    int base = blk * 1024;
    #pragma unroll
    for (int u = 0; u < 4; u++) {
        int idx = base + tid + u * 256;
        int i = (idx >> 7) & 127, j = idx & 127, b = idx >> 14;
        if (j <= i && mk[idx] != 0) {
            unsigned t = (unsigned)tc[idx], d = (unsigned)dc[idx];
            unsigned tpos = atomicAdd(&ct[t], 1u);
            wsi[ENT_T + tpos] = (unsigned)b | ((unsigned)i << 4) | ((unsigned)j << 11)
                              | (t << 18) | (d << 25);
            unsigned dpos = atomicAdd(&cd[d], 1u);
            unsigned yp = useY ? atomicAdd(&cb[(idx >> 7) & 7], 1u) : (unsigned)(idx >> 7);
            wsi[ENT_DX + dpos] = tpos;
            wsi[ENT_DP + dpos] = yp;
        }
    }
}

// phase A: xt[entry][kk] = sum_dd x[b,j][dd] * Tw[t][dd][kk]
__global__ __launch_bounds__(256) void k_phaseA(const float* __restrict__ x,
                                                const float* __restrict__ tw,
                                                unsigned* wsi, float* wsf) {
    int t = blockIdx.x, c = blockIdx.y;
    int rows = (int)wsi[CNT_T + t] - c * 128;
    if (rows <= 0) return;
    if (rows > 128) rows = 128;
    unsigned base = wsi[OFF_T + t] + c * 128;

    __shared__ float stw[4096];     // Tw[t] row-major [dd][kk]
    __shared__ float sx[8192];      // x rows, XOR-swizzled in 4-float units
    __shared__ unsigned ent[128];
    int tid = threadIdx.x;

    const float4* twg = (const float4*)(tw + t * 4096);
    float4* stw4 = (float4*)stw;
    #pragma unroll
    for (int q = 0; q < 4; q++) stw4[q * 256 + tid] = twg[q * 256 + tid];
    if (tid < 128) ent[tid] = (tid < rows) ? wsi[ENT_T + base + tid] : 0u;
    __syncthreads();

    int lane16 = tid & 15, rquot = tid >> 4;
    #pragma unroll
    for (int p = 0; p < 8; p++) {
        int r = p * 16 + rquot;
        float4 v = make_float4(0.f, 0.f, 0.f, 0.f);
        if (r < rows) {
            unsigned e = ent[r];
            int b = e & 15, j = (e >> 11) & 127;
            v = *(const float4*)(x + (b * S_ + j) * D_ + lane16 * 4);
        }
        int col4 = lane16 ^ (r & 15);
        float* dst = &sx[r * 64 + col4 * 4];
        dst[0] = v.x; dst[1] = v.y; dst[2] = v.z; dst[3] = v.w;
    }
    __syncthreads();

    int rgrp = tid & 15, cgrp = tid >> 4;   // 8 rows (rgrp+16i) x 4 cols (cgrp*4..)
    float4 acc[8];
    #pragma unroll
    for (int i = 0; i < 8; i++) acc[i] = make_float4(0.f, 0.f, 0.f, 0.f);
    #pragma unroll 4
    for (int dd = 0; dd < 64; dd++) {
        float4 w = stw4[dd * 16 + cgrp];
        int s_idx = (((dd >> 2) ^ rgrp) << 2) + (dd & 3);
        #pragma unroll
        for (int i = 0; i < 8; i++) {
            float a = sx[(rgrp + 16 * i) * 64 + s_idx];
            acc[i].x += a * w.x; acc[i].y += a * w.y;
            acc[i].z += a * w.z; acc[i].w += a * w.w;
        }
    }
    float* XT = wsf + XT_OFF;
    #pragma unroll
    for (int i = 0; i < 8; i++) {
        int r = rgrp + 16 * i;
        if (r < rows) *(float4*)(XT + (size_t)(base + r) * 64 + cgrp * 4) = acc[i];
    }
}

// phase B: y[hh] = sum_kk xt[entry][kk] * Dw[d][kk][hh]; write to Y[dstpos] (or atomic XC)
__global__ __launch_bounds__(256) void k_phaseB(const float* __restrict__ dw,
                                                unsigned* wsi, float* wsf, int useY) {
    int d = blockIdx.x, c = blockIdx.y;
    int rows = (int)wsi[CNT_D + d] - c * 128;
    if (rows <= 0) return;
    if (rows > 128) rows = 128;
    unsigned base = wsi[OFF_D + d] + c * 128;

    __shared__ float sdw[8192];     // Dw[d] row-major [kk][hh]
    __shared__ float sx[8192];      // xt rows, swizzled
    __shared__ unsigned entx[128];
    __shared__ unsigned entp[128];
    int tid = threadIdx.x;

    const float4* dwg = (const float4*)(dw + (size_t)d * 8192);
    float4* sdw4 = (float4*)sdw;
    #pragma unroll
    for (int q = 0; q < 8; q++) sdw4[q * 256 + tid] = dwg[q * 256 + tid];
    if (tid < 128) {
        entx[tid] = (tid < rows) ? wsi[ENT_DX + base + tid] : 0u;
        entp[tid] = (tid < rows) ? wsi[ENT_DP + base + tid] : 0u;
    }
    __syncthreads();

    const float* XT = wsf + XT_OFF;
    int lane16 = tid & 15, rquot = tid >> 4;
    #pragma unroll
    for (int p = 0; p < 8; p++) {
        int r = p * 16 + rquot;
        float4 v = make_float4(0.f, 0.f, 0.f, 0.f);
        if (r < rows) {
            unsigned pos = entx[r];
            v = *(const float4*)(XT + (size_t)pos * 64 + lane16 * 4);
        }
        int col4 = lane16 ^ (r & 15);
        float* dst2 = &sx[r * 64 + col4 * 4];
        dst2[0] = v.x; dst2[1] = v.y; dst2[2] = v.z; dst2[3] = v.w;
    }
    __syncthreads();

    int rgrp = tid & 15, cgrp = tid >> 4;   // 8 rows x 8 cols (cgrp*8..)
    float4 a0[8], a1[8];
    #pragma unroll
    for (int i = 0; i < 8; i++) {
        a0[i] = make_float4(0.f, 0.f, 0.f, 0.f);
        a1[i] = make_float4(0.f, 0.f, 0.f, 0.f);
    }
    #pragma unroll 2
    for (int kk = 0; kk < 64; kk++) {
        float4 w0 = sdw4[kk * 32 + cgrp * 2];
        float4 w1 = sdw4[kk * 32 + cgrp * 2 + 1];
        int s_idx = (((kk >> 2) ^ rgrp) << 2) + (kk & 3);
        #pragma unroll
        for (int i = 0; i < 8; i++) {
            float a = sx[(rgrp + 16 * i) * 64 + s_idx];
            a0[i].x += a * w0.x; a0[i].y += a * w0.y; a0[i].z += a * w0.z; a0[i].w += a * w0.w;
            a1[i].x += a * w1.x; a1[i].y += a * w1.y; a1[i].z += a * w1.z; a1[i].w += a * w1.w;
        }
    }
    if (useY) {
        float* Y = wsf + Y_OFF;
        #pragma unroll
        for (int i = 0; i < 8; i++) {
            int r = rgrp + 16 * i;
            if (r < rows) {
                float* p = Y + (size_t)entp[r] * 128 + cgrp * 8;
                *(float4*)p = a0[i];
                *(float4*)(p + 4) = a1[i];
            }
        }
    } else {
        float* XC = wsf + XC_OFF;
        #pragma unroll
        for (int i = 0; i < 8; i++) {
            int r = rgrp + 16 * i;
            if (r < rows) {
                float* p = XC + (size_t)entp[r] * 128 + cgrp * 8;
                atomicAdd(p + 0, a0[i].x); atomicAdd(p + 1, a0[i].y);
                atomicAdd(p + 2, a0[i].z); atomicAdd(p + 3, a0[i].w);
                atomicAdd(p + 4, a1[i].x); atomicAdd(p + 5, a1[i].y);
                atomicAdd(p + 6, a1[i].z); atomicAdd(p + 7, a1[i].w);
            }
        }
    }
}

// XC[b,i,:] = sum of this (b,i)'s contiguous Y rows
__global__ __launch_bounds__(128) void k_reduce(unsigned* wsi, float* wsf) {
    int bi = blockIdx.x, tid = threadIdx.x;
    unsigned n = wsi[CNT_B + bi], off = wsi[OFF_B + bi];
    const float* Yp = wsf + Y_OFF + (size_t)off * 128 + tid;
    float a0 = 0.f, a1 = 0.f, a2 = 0.f, a3 = 0.f;
    unsigned e = 0;
    for (; e + 4 <= n; e += 4) {
        a0 += Yp[(size_t)e * 128];
        a1 += Yp[(size_t)(e + 1) * 128];
        a2 += Yp[(size_t)(e + 2) * 128];
        a3 += Yp[(size_t)(e + 3) * 128];
    }
    for (; e < n; e++) a0 += Yp[(size_t)e * 128];
    wsf[XC_OFF + (size_t)bi * 128 + tid] = (a0 + a1) + (a2 + a3);
}

// recurrence: h_new = sigmoid(XC[b,i] + h @ Wh); one block per batch b
__global__ __launch_bounds__(512) void k_recur(const float* __restrict__ hw,
                                               const float* __restrict__ wsf,
                                               float* __restrict__ out) {
    int b = blockIdx.x;
    __shared__ float swh[16384];    // Wh row-major [k][h']
    __shared__ float sh[128];
    __shared__ float part[4][128];
    int tid = threadIdx.x;

    float4* swh4 = (float4*)swh;
    const float4* hwg = (const float4*)hw;
    #pragma unroll
    for (int q = 0; q < 8; q++) swh4[q * 512 + tid] = hwg[q * 512 + tid];
    if (tid < 128) sh[tid] = 0.f;
    __syncthreads();

    int hp = tid & 127, seg = tid >> 7;   // 4 segs x 32 k each
    int k0 = seg * 32;
    for (int i = 0; i < 128; i++) {
        float acc0 = (seg == 0) ? wsf[XC_OFF + ((size_t)(b * 128 + i)) * 128 + hp] : 0.f;
        float acc1 = 0.f, acc2 = 0.f, acc3 = 0.f;
        #pragma unroll 8
        for (int k = k0; k < k0 + 32; k += 4) {
            acc0 += sh[k + 0] * swh[(k + 0) * 128 + hp];
            acc1 += sh[k + 1] * swh[(k + 1) * 128 + hp];
            acc2 += sh[k + 2] * swh[(k + 2) * 128 + hp];
            acc3 += sh[k + 3] * swh[(k + 3) * 128 + hp];
        }
        part[seg][hp] = (acc0 + acc1) + (acc2 + acc3);
        __syncthreads();
        if (tid < 128) {
            float v = (part[0][hp] + part[1][hp]) + (part[2][hp] + part[3][hp]);
            v = 1.f / (1.f + expf(-v));
            sh[hp] = v;
            out[((size_t)(b * 128 + i)) * 128 + hp] = v;
        }
        __syncthreads();
    }
    if (tid < 128) out[(size_t)B_ * S_ * H_ + b * 128 + hp] = sh[hp];
}

extern "C" void kernel_launch(void* const* d_in, const int* in_sizes, int n_in,
                              void* d_out, int out_size, void* d_ws, size_t ws_size,
                              hipStream_t stream) {
    const float* x  = (const float*)d_in[0];
    const int*   tc = (const int*)d_in[1];
    const int*   dc = (const int*)d_in[2];
    const int*   mk = (const int*)d_in[3];   // bool masks pushed as int32
    const float* tw = (const float*)d_in[4];
    const float* dw = (const float*)d_in[5];
    const float* hw = (const float*)d_in[6];
    float*    out = (float*)d_out;
    float*    wsf = (float*)d_ws;
    unsigned* wsi = (unsigned*)d_ws;
    char*     wsb = (char*)d_ws;

    int useY = (ws_size >= NEED_BYTES) ? 1 : 0;
    if (!useY)  // fallback path accumulates into XC with atomics -> needs zeroed XC
        hipMemsetAsync(wsb, 0, (size_t)262144 * 4, stream);

    k_hist1<<<dim3(256), dim3(256), 0, stream>>>(tc, dc, mk, wsi);
    k_scan_all<<<dim3(1), dim3(1024), 0, stream>>>(wsi);
    k_scatter<<<dim3(256), dim3(256), 0, stream>>>(tc, dc, mk, wsi, useY);
    k_phaseA<<<dim3(NS, 16), dim3(256), 0, stream>>>(x, tw, wsi, wsf);
    k_phaseB<<<dim3(NS, 16), dim3(256), 0, stream>>>(dw, wsi, wsf, useY);
    if (useY) k_reduce<<<dim3(2048), dim3(128), 0, stream>>>(wsi, wsf);
    k_recur<<<dim3(16), dim3(512), 0, stream>>>(hw, wsf, out);
}

// Round 4
// 198.159 us; speedup vs baseline: 3.3196x; 1.0098x over previous
//
#include <hip/hip_runtime.h>
#include <math.h>

// STRNN: B=16, S=128, D=64, K=64, H=128, NSLOT+1=97 slots.
//
// Pipeline (all f32), no contended global atomics:
//  k_hist1    : per-block LDS histograms of t-slot / d-slot / per-(b,i) counts
//  k_scan_all : exclusive scans -> per-(bin,block) bases + OFF_T/OFF_D/OFF_B
//  k_scatter  : one pass; LDS cursors; emits t-sorted entries, d-sorted refs, Y slots
//  k_phaseA   : per t-bucket GEMM  xt = x[b,j] @ Tw[t]   (Tw in LDS) -> XT[tpos][64]
//  k_phaseB   : per d-bucket GEMM  y = xt @ Dw[d] (Dw in LDS) -> Y[dstpos][128]
//  k_reduce   : XC[b,i,:] = sum of its contiguous Y rows
//  k_recur    : h = sigmoid(XC[b,i] + h@Wh); Wh in REGISTERS (128/thread),
//               h broadcast-read from LDS, double-buffered, 1 barrier/step
//
// ws requirement: ~104.3 MB for the atomic-free path (guarded; fallback = atomicAdd XC).

#define B_ 16
#define S_ 128
#define D_ 64
#define K_ 64
#define H_ 128
#define NS 97
#define MAXE 132096  // B * S*(S+1)/2  (upper bound on valid triples)

// u32/f32-index offsets into ws
#define XC_OFF 0                  // f32 [2048][128]
#define BH_T   262144             // u32 [97][256]  per-(bin,block) hist -> bases
#define BH_D   (BH_T + 24832)     // u32 [97][256]
#define CNT_T  (BH_D + 24832)     // u32 [97]
#define CNT_D  (CNT_T + 97)       // u32 [97]
#define CNT_B  (CNT_D + 97)       // u32 [2048]
#define OFF_T  (CNT_B + 2048)     // u32 [98] (last = total)
#define OFF_D  (OFF_T + 98)       // u32 [98]
#define OFF_B  (OFF_D + 98)       // u32 [2049]
#define ENT_T  316296             // u32 [MAXE] packed: b|i<<4|j<<11|t<<18|d<<25 (16B-aligned)
#define ENT_DX (ENT_T + MAXE)     // u32 [MAXE] xt-row index (t-sorted pos)
#define ENT_DP (ENT_DX + MAXE)    // u32 [MAXE] Y-row (dst-sorted pos) [or dst in fallback]
#define XT_OFF (ENT_DP + MAXE)    // f32 [MAXE][64]
#define Y_OFF  (XT_OFF + MAXE * 64)            // f32 [MAXE][128]
#define NEED_BYTES ((size_t)(Y_OFF + (size_t)MAXE * 128) * 4)

// ---- binning: 256 blocks x 1024 elements (8 full (b,i) rows per block) ----

__global__ __launch_bounds__(256) void k_hist1(const int* __restrict__ tc,
                                               const int* __restrict__ dc,
                                               const int* __restrict__ mk,
                                               unsigned* wsi) {
    __shared__ unsigned ht[NS], hd[NS], hb[8];
    int tid = threadIdx.x, blk = blockIdx.x;
    if (tid < NS) { ht[tid] = 0; hd[tid] = 0; }
    if (tid < 8) hb[tid] = 0;
    __syncthreads();
    int base = blk * 1024;
    #pragma unroll
    for (int u = 0; u < 4; u++) {
        int idx = base + tid + u * 256;
        int i = (idx >> 7) & 127, j = idx & 127;
        if (j <= i && mk[idx] != 0) {
            atomicAdd(&ht[tc[idx]], 1u);
            atomicAdd(&hd[dc[idx]], 1u);
            atomicAdd(&hb[(idx >> 7) & 7], 1u);
        }
    }
    __syncthreads();
    if (tid < NS) {
        wsi[BH_T + tid * 256 + blk] = ht[tid];
        wsi[BH_D + tid * 256 + blk] = hd[tid];
    }
    if (tid < 8) wsi[CNT_B + blk * 8 + tid] = hb[tid];
}

template <int CH>
__device__ unsigned scan_region(unsigned* in, unsigned* out, int L, unsigned* s) {
    int tid = threadIdx.x;
    unsigned loc[CH], sum = 0;
    #pragma unroll
    for (int k = 0; k < CH; k++) {
        int idx = tid * CH + k;
        loc[k] = (idx < L) ? in[idx] : 0u;
        sum += loc[k];
    }
    s[tid] = sum;
    __syncthreads();
    for (int o = 1; o < 1024; o <<= 1) {
        unsigned a = (tid >= o) ? s[tid - o] : 0u;
        __syncthreads();
        s[tid] += a;
        __syncthreads();
    }
    unsigned total = s[1023];
    unsigned run = s[tid] - sum;
    __syncthreads();
    #pragma unroll
    for (int k = 0; k < CH; k++) {
        int idx = tid * CH + k;
        if (idx < L) { out[idx] = run; run += loc[k]; }
    }
    __syncthreads();
    return total;
}

__global__ __launch_bounds__(1024) void k_scan_all(unsigned* wsi) {
    __shared__ unsigned s[1024];
    int tid = threadIdx.x;

    unsigned totT = scan_region<25>(wsi + BH_T, wsi + BH_T, NS * 256, s);
    if (tid < NS) {
        unsigned b0 = wsi[BH_T + tid * 256];
        unsigned b1 = (tid < NS - 1) ? wsi[BH_T + (tid + 1) * 256] : totT;
        wsi[OFF_T + tid] = b0;
        wsi[CNT_T + tid] = b1 - b0;
    }
    if (tid == 0) wsi[OFF_T + NS] = totT;
    __syncthreads();

    unsigned totD = scan_region<25>(wsi + BH_D, wsi + BH_D, NS * 256, s);
    if (tid < NS) {
        unsigned b0 = wsi[BH_D + tid * 256];
        unsigned b1 = (tid < NS - 1) ? wsi[BH_D + (tid + 1) * 256] : totD;
        wsi[OFF_D + tid] = b0;
        wsi[CNT_D + tid] = b1 - b0;
    }
    if (tid == 0) wsi[OFF_D + NS] = totD;
    __syncthreads();

    unsigned totB = scan_region<2>(wsi + CNT_B, wsi + OFF_B, 2048, s);
    if (tid == 0) wsi[OFF_B + 2048] = totB;
}

__global__ __launch_bounds__(256) void k_scatter(const int* __restrict__ tc,
                                                 const int* __restrict__ dc,
                                                 const int* __restrict__ mk,
                                                 unsigned* wsi, int useY) {
    __shared__ unsigned ct[NS], cd[NS], cb[8];
    int tid = threadIdx.x, blk = blockIdx.x;
    if (tid < NS) {
        ct[tid] = wsi[BH_T + tid * 256 + blk];
        cd[tid] = wsi[BH_D + tid * 256 + blk];
    }
    if (tid < 8) cb[tid] = wsi[OFF_B + blk * 8 + tid];
    __syncthreads();
    int base = blk * 1024;
    #pragma unroll
    for (int u = 0; u < 4; u++) {
        int idx = base + tid + u * 256;
        int i = (idx >> 7) & 127, j = idx & 127, b = idx >> 14;
        if (j <= i && mk[idx] != 0) {
            unsigned t = (unsigned)tc[idx], d = (unsigned)dc[idx];
            unsigned tpos = atomicAdd(&ct[t], 1u);
            wsi[ENT_T + tpos] = (unsigned)b | ((unsigned)i << 4) | ((unsigned)j << 11)
                              | (t << 18) | (d << 25);
            unsigned dpos = atomicAdd(&cd[d], 1u);
            unsigned yp = useY ? atomicAdd(&cb[(idx >> 7) & 7], 1u) : (unsigned)(idx >> 7);
            wsi[ENT_DX + dpos] = tpos;
            wsi[ENT_DP + dpos] = yp;
        }
    }
}

// phase A: xt[entry][kk] = sum_dd x[b,j][dd] * Tw[t][dd][kk]
__global__ __launch_bounds__(256) void k_phaseA(const float* __restrict__ x,
                                                const float* __restrict__ tw,
                                                unsigned* wsi, float* wsf) {
    int t = blockIdx.x, c = blockIdx.y;
    int rows = (int)wsi[CNT_T + t] - c * 128;
    if (rows <= 0) return;
    if (rows > 128) rows = 128;
    unsigned base = wsi[OFF_T + t] + c * 128;

    __shared__ float stw[4096];     // Tw[t] row-major [dd][kk]
    __shared__ float sx[8192];      // x rows, XOR-swizzled in 4-float units
    __shared__ unsigned ent[128];
    int tid = threadIdx.x;

    const float4* twg = (const float4*)(tw + t * 4096);
    float4* stw4 = (float4*)stw;
    #pragma unroll
    for (int q = 0; q < 4; q++) stw4[q * 256 + tid] = twg[q * 256 + tid];
    if (tid < 128) ent[tid] = (tid < rows) ? wsi[ENT_T + base + tid] : 0u;
    __syncthreads();

    int lane16 = tid & 15, rquot = tid >> 4;
    #pragma unroll
    for (int p = 0; p < 8; p++) {
        int r = p * 16 + rquot;
        float4 v = make_float4(0.f, 0.f, 0.f, 0.f);
        if (r < rows) {
            unsigned e = ent[r];
            int b = e & 15, j = (e >> 11) & 127;
            v = *(const float4*)(x + (b * S_ + j) * D_ + lane16 * 4);
        }
        int col4 = lane16 ^ (r & 15);
        float* dst = &sx[r * 64 + col4 * 4];
        dst[0] = v.x; dst[1] = v.y; dst[2] = v.z; dst[3] = v.w;
    }
    __syncthreads();

    int rgrp = tid & 15, cgrp = tid >> 4;   // 8 rows (rgrp+16i) x 4 cols (cgrp*4..)
    float4 acc[8];
    #pragma unroll
    for (int i = 0; i < 8; i++) acc[i] = make_float4(0.f, 0.f, 0.f, 0.f);
    #pragma unroll 4
    for (int dd = 0; dd < 64; dd++) {
        float4 w = stw4[dd * 16 + cgrp];
        int s_idx = (((dd >> 2) ^ rgrp) << 2) + (dd & 3);
        #pragma unroll
        for (int i = 0; i < 8; i++) {
            float a = sx[(rgrp + 16 * i) * 64 + s_idx];
            acc[i].x += a * w.x; acc[i].y += a * w.y;
            acc[i].z += a * w.z; acc[i].w += a * w.w;
        }
    }
    float* XT = wsf + XT_OFF;
    #pragma unroll
    for (int i = 0; i < 8; i++) {
        int r = rgrp + 16 * i;
        if (r < rows) *(float4*)(XT + (size_t)(base + r) * 64 + cgrp * 4) = acc[i];
    }
}

// phase B: y[hh] = sum_kk xt[entry][kk] * Dw[d][kk][hh]; write to Y[dstpos] (or atomic XC)
__global__ __launch_bounds__(256) void k_phaseB(const float* __restrict__ dw,
                                                unsigned* wsi, float* wsf, int useY) {
    int d = blockIdx.x, c = blockIdx.y;
    int rows = (int)wsi[CNT_D + d] - c * 128;
    if (rows <= 0) return;
    if (rows > 128) rows = 128;
    unsigned base = wsi[OFF_D + d] + c * 128;

    __shared__ float sdw[8192];     // Dw[d] row-major [kk][hh]
    __shared__ float sx[8192];      // xt rows, swizzled
    __shared__ unsigned entx[128];
    __shared__ unsigned entp[128];
    int tid = threadIdx.x;

    const float4* dwg = (const float4*)(dw + (size_t)d * 8192);
    float4* sdw4 = (float4*)sdw;
    #pragma unroll
    for (int q = 0; q < 8; q++) sdw4[q * 256 + tid] = dwg[q * 256 + tid];
    if (tid < 128) {
        entx[tid] = (tid < rows) ? wsi[ENT_DX + base + tid] : 0u;
        entp[tid] = (tid < rows) ? wsi[ENT_DP + base + tid] : 0u;
    }
    __syncthreads();

    const float* XT = wsf + XT_OFF;
    int lane16 = tid & 15, rquot = tid >> 4;
    #pragma unroll
    for (int p = 0; p < 8; p++) {
        int r = p * 16 + rquot;
        float4 v = make_float4(0.f, 0.f, 0.f, 0.f);
        if (r < rows) {
            unsigned pos = entx[r];
            v = *(const float4*)(XT + (size_t)pos * 64 + lane16 * 4);
        }
        int col4 = lane16 ^ (r & 15);
        float* dst2 = &sx[r * 64 + col4 * 4];
        dst2[0] = v.x; dst2[1] = v.y; dst2[2] = v.z; dst2[3] = v.w;
    }
    __syncthreads();

    int rgrp = tid & 15, cgrp = tid >> 4;   // 8 rows x 8 cols (cgrp*8..)
    float4 a0[8], a1[8];
    #pragma unroll
    for (int i = 0; i < 8; i++) {
        a0[i] = make_float4(0.f, 0.f, 0.f, 0.f);
        a1[i] = make_float4(0.f, 0.f, 0.f, 0.f);
    }
    #pragma unroll 2
    for (int kk = 0; kk < 64; kk++) {
        float4 w0 = sdw4[kk * 32 + cgrp * 2];
        float4 w1 = sdw4[kk * 32 + cgrp * 2 + 1];
        int s_idx = (((kk >> 2) ^ rgrp) << 2) + (kk & 3);
        #pragma unroll
        for (int i = 0; i < 8; i++) {
            float a = sx[(rgrp + 16 * i) * 64 + s_idx];
            a0[i].x += a * w0.x; a0[i].y += a * w0.y; a0[i].z += a * w0.z; a0[i].w += a * w0.w;
            a1[i].x += a * w1.x; a1[i].y += a * w1.y; a1[i].z += a * w1.z; a1[i].w += a * w1.w;
        }
    }
    if (useY) {
        float* Y = wsf + Y_OFF;
        #pragma unroll
        for (int i = 0; i < 8; i++) {
            int r = rgrp + 16 * i;
            if (r < rows) {
                float* p = Y + (size_t)entp[r] * 128 + cgrp * 8;
                *(float4*)p = a0[i];
                *(float4*)(p + 4) = a1[i];
            }
        }
    } else {
        float* XC = wsf + XC_OFF;
        #pragma unroll
        for (int i = 0; i < 8; i++) {
            int r = rgrp + 16 * i;
            if (r < rows) {
                float* p = XC + (size_t)entp[r] * 128 + cgrp * 8;
                atomicAdd(p + 0, a0[i].x); atomicAdd(p + 1, a0[i].y);
                atomicAdd(p + 2, a0[i].z); atomicAdd(p + 3, a0[i].w);
                atomicAdd(p + 4, a1[i].x); atomicAdd(p + 5, a1[i].y);
                atomicAdd(p + 6, a1[i].z); atomicAdd(p + 7, a1[i].w);
            }
        }
    }
}

// XC[b,i,:] = sum of this (b,i)'s contiguous Y rows
__global__ __launch_bounds__(128) void k_reduce(unsigned* wsi, float* wsf) {
    int bi = blockIdx.x, tid = threadIdx.x;
    unsigned n = wsi[CNT_B + bi], off = wsi[OFF_B + bi];
    const float* Yp = wsf + Y_OFF + (size_t)off * 128 + tid;
    float a0 = 0.f, a1 = 0.f, a2 = 0.f, a3 = 0.f;
    unsigned e = 0;
    for (; e + 4 <= n; e += 4) {
        a0 += Yp[(size_t)e * 128];
        a1 += Yp[(size_t)(e + 1) * 128];
        a2 += Yp[(size_t)(e + 2) * 128];
        a3 += Yp[(size_t)(e + 3) * 128];
    }
    for (; e < n; e++) a0 += Yp[(size_t)e * 128];
    wsf[XC_OFF + (size_t)bi * 128 + tid] = (a0 + a1) + (a2 + a3);
}

// recurrence: h_new = sigmoid(XC[b,i] + h @ Wh); one block (128 thr) per batch b.
// Wh column hp=tid lives in 128 VGPRs; h is broadcast-read from double-buffered LDS.
__global__ __launch_bounds__(128) void k_recur(const float* __restrict__ hw,
                                               const float* __restrict__ wsf,
                                               float* __restrict__ out) {
    int b = blockIdx.x;
    __shared__ float swh[16384];    // staging for weight transpose (used once)
    __shared__ float sh[2][128];
    int tid = threadIdx.x;          // 0..127 == output column hp

    // coalesced load of Wh into LDS, then pull column tid into registers
    const float4* hwg = (const float4*)hw;
    float4* swh4 = (float4*)swh;
    #pragma unroll
    for (int q = 0; q < 32; q++) swh4[q * 128 + tid] = hwg[q * 128 + tid];
    sh[0][tid] = 0.f;
    __syncthreads();
    float w[128];
    #pragma unroll
    for (int k = 0; k < 128; k++) w[k] = swh[k * 128 + tid];  // 2 lanes/bank: free

    const float* XC = wsf + XC_OFF + (size_t)b * 128 * 128;
    float xc_next = XC[tid];        // row 0 prefetch
    int cur = 0;
    for (int i = 0; i < 128; i++) {
        float xc = xc_next;
        if (i < 127) xc_next = XC[(i + 1) * 128 + tid];   // prefetch next row
        const float4* s4 = (const float4*)sh[cur];
        float acc0 = 0.f, acc1 = 0.f, acc2 = 0.f, acc3 = 0.f;
        #pragma unroll
        for (int kk = 0; kk < 32; kk++) {                 // 32 b128 broadcast reads
            float4 v = s4[kk];
            acc0 += v.x * w[4 * kk + 0];
            acc1 += v.y * w[4 * kk + 1];
            acc2 += v.z * w[4 * kk + 2];
            acc3 += v.w * w[4 * kk + 3];
        }
        float val = xc + (acc0 + acc1) + (acc2 + acc3);
        val = 1.f / (1.f + __expf(-val));
        sh[cur ^ 1][tid] = val;
        out[(size_t)(b * 128 + i) * 128 + tid] = val;
        cur ^= 1;
        __syncthreads();
    }
    out[(size_t)B_ * S_ * H_ + b * 128 + tid] = sh[cur][tid];
}

extern "C" void kernel_launch(void* const* d_in, const int* in_sizes, int n_in,
                              void* d_out, int out_size, void* d_ws, size_t ws_size,
                              hipStream_t stream) {
    const float* x  = (const float*)d_in[0];
    const int*   tc = (const int*)d_in[1];
    const int*   dc = (const int*)d_in[2];
    const int*   mk = (const int*)d_in[3];   // bool masks pushed as int32
    const float* tw = (const float*)d_in[4];
    const float* dw = (const float*)d_in[5];
    const float* hw = (const float*)d_in[6];
    float*    out = (float*)d_out;
    float*    wsf = (float*)d_ws;
    unsigned* wsi = (unsigned*)d_ws;
    char*     wsb = (char*)d_ws;

    int useY = (ws_size >= NEED_BYTES) ? 1 : 0;
    if (!useY)  // fallback path accumulates into XC with atomics -> needs zeroed XC
        hipMemsetAsync(wsb, 0, (size_t)262144 * 4, stream);

    k_hist1<<<dim3(256), dim3(256), 0, stream>>>(tc, dc, mk, wsi);
    k_scan_all<<<dim3(1), dim3(1024), 0, stream>>>(wsi);
    k_scatter<<<dim3(256), dim3(256), 0, stream>>>(tc, dc, mk, wsi, useY);
    k_phaseA<<<dim3(NS, 16), dim3(256), 0, stream>>>(x, tw, wsi, wsf);
    k_phaseB<<<dim3(NS, 16), dim3(256), 0, stream>>>(dw, wsi, wsf, useY);
    if (useY) k_reduce<<<dim3(2048), dim3(128), 0, stream>>>(wsi, wsf);
    k_recur<<<dim3(16), dim3(128), 0, stream>>>(hw, wsf, out);
}

// Round 5
// 172.288 us; speedup vs baseline: 3.8181x; 1.1502x over previous
//
#include <hip/hip_runtime.h>
#include <math.h>

// STRNN: B=16, S=128, D=64, K=64, H=128, NSLOT+1=97 slots.
//
// Pipeline (all f32), no contended global atomics:
//  k_hist1    : per-block LDS histograms of t-slot / d-slot / per-(b,i) counts
//  k_scan_all : exclusive scans -> per-(bin,block) bases + OFF_T/OFF_D/OFF_B
//  k_scatter  : one pass; LDS cursors; emits t-sorted entries, d-sorted refs, Y slots
//  k_phaseA   : per t-bucket GEMM  xt = x[b,j] @ Tw[t]   (Tw in LDS) -> XT[tpos][64]
//  k_phaseB   : per d-bucket GEMM  y = xt @ Dw[d] (Dw in LDS) -> Y[dstpos][128]
//  k_reduce   : XC[b,i,:] = sum of its contiguous Y rows
//  k_recur    : h = sigmoid(XC[b,i] + h@Wh); 256 thr/block, thread (col,khalf)
//               holds w[64] in VGPRs (no spill), K-halves combined via shfl_xor,
//               ONE barrier per step.
//
// ws requirement: ~104.3 MB for the atomic-free path (guarded; fallback = atomicAdd XC).

#define B_ 16
#define S_ 128
#define D_ 64
#define K_ 64
#define H_ 128
#define NS 97
#define MAXE 132096  // B * S*(S+1)/2  (upper bound on valid triples)

// u32/f32-index offsets into ws
#define XC_OFF 0                  // f32 [2048][128]
#define BH_T   262144             // u32 [97][256]  per-(bin,block) hist -> bases
#define BH_D   (BH_T + 24832)     // u32 [97][256]
#define CNT_T  (BH_D + 24832)     // u32 [97]
#define CNT_D  (CNT_T + 97)       // u32 [97]
#define CNT_B  (CNT_D + 97)       // u32 [2048]
#define OFF_T  (CNT_B + 2048)     // u32 [98] (last = total)
#define OFF_D  (OFF_T + 98)       // u32 [98]
#define OFF_B  (OFF_D + 98)       // u32 [2049]
#define ENT_T  316296             // u32 [MAXE] packed: b|i<<4|j<<11|t<<18|d<<25 (16B-aligned)
#define ENT_DX (ENT_T + MAXE)     // u32 [MAXE] xt-row index (t-sorted pos)
#define ENT_DP (ENT_DX + MAXE)    // u32 [MAXE] Y-row (dst-sorted pos) [or dst in fallback]
#define XT_OFF (ENT_DP + MAXE)    // f32 [MAXE][64]
#define Y_OFF  (XT_OFF + MAXE * 64)            // f32 [MAXE][128]
#define NEED_BYTES ((size_t)(Y_OFF + (size_t)MAXE * 128) * 4)

// ---- binning: 256 blocks x 1024 elements (8 full (b,i) rows per block) ----

__global__ __launch_bounds__(256) void k_hist1(const int* __restrict__ tc,
                                               const int* __restrict__ dc,
                                               const int* __restrict__ mk,
                                               unsigned* wsi) {
    __shared__ unsigned ht[NS], hd[NS], hb[8];
    int tid = threadIdx.x, blk = blockIdx.x;
    if (tid < NS) { ht[tid] = 0; hd[tid] = 0; }
    if (tid < 8) hb[tid] = 0;
    __syncthreads();
    int base = blk * 1024;
    #pragma unroll
    for (int u = 0; u < 4; u++) {
        int idx = base + tid + u * 256;
        int i = (idx >> 7) & 127, j = idx & 127;
        if (j <= i && mk[idx] != 0) {
            atomicAdd(&ht[tc[idx]], 1u);
            atomicAdd(&hd[dc[idx]], 1u);
            atomicAdd(&hb[(idx >> 7) & 7], 1u);
        }
    }
    __syncthreads();
    if (tid < NS) {
        wsi[BH_T + tid * 256 + blk] = ht[tid];
        wsi[BH_D + tid * 256 + blk] = hd[tid];
    }
    if (tid < 8) wsi[CNT_B + blk * 8 + tid] = hb[tid];
}

template <int CH>
__device__ unsigned scan_region(unsigned* in, unsigned* out, int L, unsigned* s) {
    int tid = threadIdx.x;
    unsigned loc[CH], sum = 0;
    #pragma unroll
    for (int k = 0; k < CH; k++) {
        int idx = tid * CH + k;
        loc[k] = (idx < L) ? in[idx] : 0u;
        sum += loc[k];
    }
    s[tid] = sum;
    __syncthreads();
    for (int o = 1; o < 1024; o <<= 1) {
        unsigned a = (tid >= o) ? s[tid - o] : 0u;
        __syncthreads();
        s[tid] += a;
        __syncthreads();
    }
    unsigned total = s[1023];
    unsigned run = s[tid] - sum;
    __syncthreads();
    #pragma unroll
    for (int k = 0; k < CH; k++) {
        int idx = tid * CH + k;
        if (idx < L) { out[idx] = run; run += loc[k]; }
    }
    __syncthreads();
    return total;
}

__global__ __launch_bounds__(1024) void k_scan_all(unsigned* wsi) {
    __shared__ unsigned s[1024];
    int tid = threadIdx.x;

    unsigned totT = scan_region<25>(wsi + BH_T, wsi + BH_T, NS * 256, s);
    if (tid < NS) {
        unsigned b0 = wsi[BH_T + tid * 256];
        unsigned b1 = (tid < NS - 1) ? wsi[BH_T + (tid + 1) * 256] : totT;
        wsi[OFF_T + tid] = b0;
        wsi[CNT_T + tid] = b1 - b0;
    }
    if (tid == 0) wsi[OFF_T + NS] = totT;
    __syncthreads();

    unsigned totD = scan_region<25>(wsi + BH_D, wsi + BH_D, NS * 256, s);
    if (tid < NS) {
        unsigned b0 = wsi[BH_D + tid * 256];
        unsigned b1 = (tid < NS - 1) ? wsi[BH_D + (tid + 1) * 256] : totD;
        wsi[OFF_D + tid] = b0;
        wsi[CNT_D + tid] = b1 - b0;
    }
    if (tid == 0) wsi[OFF_D + NS] = totD;
    __syncthreads();

    unsigned totB = scan_region<2>(wsi + CNT_B, wsi + OFF_B, 2048, s);
    if (tid == 0) wsi[OFF_B + 2048] = totB;
}

__global__ __launch_bounds__(256) void k_scatter(const int* __restrict__ tc,
                                                 const int* __restrict__ dc,
                                                 const int* __restrict__ mk,
                                                 unsigned* wsi, int useY) {
    __shared__ unsigned ct[NS], cd[NS], cb[8];
    int tid = threadIdx.x, blk = blockIdx.x;
    if (tid < NS) {
        ct[tid] = wsi[BH_T + tid * 256 + blk];
        cd[tid] = wsi[BH_D + tid * 256 + blk];
    }
    if (tid < 8) cb[tid] = wsi[OFF_B + blk * 8 + tid];
    __syncthreads();
    int base = blk * 1024;
    #pragma unroll
    for (int u = 0; u < 4; u++) {
        int idx = base + tid + u * 256;
        int i = (idx >> 7) & 127, j = idx & 127, b = idx >> 14;
        if (j <= i && mk[idx] != 0) {
            unsigned t = (unsigned)tc[idx], d = (unsigned)dc[idx];
            unsigned tpos = atomicAdd(&ct[t], 1u);
            wsi[ENT_T + tpos] = (unsigned)b | ((unsigned)i << 4) | ((unsigned)j << 11)
                              | (t << 18) | (d << 25);
            unsigned dpos = atomicAdd(&cd[d], 1u);
            unsigned yp = useY ? atomicAdd(&cb[(idx >> 7) & 7], 1u) : (unsigned)(idx >> 7);
            wsi[ENT_DX + dpos] = tpos;
            wsi[ENT_DP + dpos] = yp;
        }
    }
}

// phase A: xt[entry][kk] = sum_dd x[b,j][dd] * Tw[t][dd][kk]
__global__ __launch_bounds__(256) void k_phaseA(const float* __restrict__ x,
                                                const float* __restrict__ tw,
                                                unsigned* wsi, float* wsf) {
    int t = blockIdx.x, c = blockIdx.y;
    int rows = (int)wsi[CNT_T + t] - c * 128;
    if (rows <= 0) return;
    if (rows > 128) rows = 128;
    unsigned base = wsi[OFF_T + t] + c * 128;

    __shared__ float stw[4096];     // Tw[t] row-major [dd][kk]
    __shared__ float sx[8192];      // x rows, XOR-swizzled in 4-float units
    __shared__ unsigned ent[128];
    int tid = threadIdx.x;

    const float4* twg = (const float4*)(tw + t * 4096);
    float4* stw4 = (float4*)stw;
    #pragma unroll
    for (int q = 0; q < 4; q++) stw4[q * 256 + tid] = twg[q * 256 + tid];
    if (tid < 128) ent[tid] = (tid < rows) ? wsi[ENT_T + base + tid] : 0u;
    __syncthreads();

    int lane16 = tid & 15, rquot = tid >> 4;
    #pragma unroll
    for (int p = 0; p < 8; p++) {
        int r = p * 16 + rquot;
        float4 v = make_float4(0.f, 0.f, 0.f, 0.f);
        if (r < rows) {
            unsigned e = ent[r];
            int b = e & 15, j = (e >> 11) & 127;
            v = *(const float4*)(x + (b * S_ + j) * D_ + lane16 * 4);
        }
        int col4 = lane16 ^ (r & 15);
        float* dst = &sx[r * 64 + col4 * 4];
        dst[0] = v.x; dst[1] = v.y; dst[2] = v.z; dst[3] = v.w;
    }
    __syncthreads();

    int rgrp = tid & 15, cgrp = tid >> 4;   // 8 rows (rgrp+16i) x 4 cols (cgrp*4..)
    float4 acc[8];
    #pragma unroll
    for (int i = 0; i < 8; i++) acc[i] = make_float4(0.f, 0.f, 0.f, 0.f);
    #pragma unroll 4
    for (int dd = 0; dd < 64; dd++) {
        float4 w = stw4[dd * 16 + cgrp];
        int s_idx = (((dd >> 2) ^ rgrp) << 2) + (dd & 3);
        #pragma unroll
        for (int i = 0; i < 8; i++) {
            float a = sx[(rgrp + 16 * i) * 64 + s_idx];
            acc[i].x += a * w.x; acc[i].y += a * w.y;
            acc[i].z += a * w.z; acc[i].w += a * w.w;
        }
    }
    float* XT = wsf + XT_OFF;
    #pragma unroll
    for (int i = 0; i < 8; i++) {
        int r = rgrp + 16 * i;
        if (r < rows) *(float4*)(XT + (size_t)(base + r) * 64 + cgrp * 4) = acc[i];
    }
}

// phase B: y[hh] = sum_kk xt[entry][kk] * Dw[d][kk][hh]; write to Y[dstpos] (or atomic XC)
__global__ __launch_bounds__(256) void k_phaseB(const float* __restrict__ dw,
                                                unsigned* wsi, float* wsf, int useY) {
    int d = blockIdx.x, c = blockIdx.y;
    int rows = (int)wsi[CNT_D + d] - c * 128;
    if (rows <= 0) return;
    if (rows > 128) rows = 128;
    unsigned base = wsi[OFF_D + d] + c * 128;

    __shared__ float sdw[8192];     // Dw[d] row-major [kk][hh]
    __shared__ float sx[8192];      // xt rows, swizzled
    __shared__ unsigned entx[128];
    __shared__ unsigned entp[128];
    int tid = threadIdx.x;

    const float4* dwg = (const float4*)(dw + (size_t)d * 8192);
    float4* sdw4 = (float4*)sdw;
    #pragma unroll
    for (int q = 0; q < 8; q++) sdw4[q * 256 + tid] = dwg[q * 256 + tid];
    if (tid < 128) {
        entx[tid] = (tid < rows) ? wsi[ENT_DX + base + tid] : 0u;
        entp[tid] = (tid < rows) ? wsi[ENT_DP + base + tid] : 0u;
    }
    __syncthreads();

    const float* XT = wsf + XT_OFF;
    int lane16 = tid & 15, rquot = tid >> 4;
    #pragma unroll
    for (int p = 0; p < 8; p++) {
        int r = p * 16 + rquot;
        float4 v = make_float4(0.f, 0.f, 0.f, 0.f);
        if (r < rows) {
            unsigned pos = entx[r];
            v = *(const float4*)(XT + (size_t)pos * 64 + lane16 * 4);
        }
        int col4 = lane16 ^ (r & 15);
        float* dst2 = &sx[r * 64 + col4 * 4];
        dst2[0] = v.x; dst2[1] = v.y; dst2[2] = v.z; dst2[3] = v.w;
    }
    __syncthreads();

    int rgrp = tid & 15, cgrp = tid >> 4;   // 8 rows x 8 cols (cgrp*8..)
    float4 a0[8], a1[8];
    #pragma unroll
    for (int i = 0; i < 8; i++) {
        a0[i] = make_float4(0.f, 0.f, 0.f, 0.f);
        a1[i] = make_float4(0.f, 0.f, 0.f, 0.f);
    }
    #pragma unroll 2
    for (int kk = 0; kk < 64; kk++) {
        float4 w0 = sdw4[kk * 32 + cgrp * 2];
        float4 w1 = sdw4[kk * 32 + cgrp * 2 + 1];
        int s_idx = (((kk >> 2) ^ rgrp) << 2) + (kk & 3);
        #pragma unroll
        for (int i = 0; i < 8; i++) {
            float a = sx[(rgrp + 16 * i) * 64 + s_idx];
            a0[i].x += a * w0.x; a0[i].y += a * w0.y; a0[i].z += a * w0.z; a0[i].w += a * w0.w;
            a1[i].x += a * w1.x; a1[i].y += a * w1.y; a1[i].z += a * w1.z; a1[i].w += a * w1.w;
        }
    }
    if (useY) {
        float* Y = wsf + Y_OFF;
        #pragma unroll
        for (int i = 0; i < 8; i++) {
            int r = rgrp + 16 * i;
            if (r < rows) {
                float* p = Y + (size_t)entp[r] * 128 + cgrp * 8;
                *(float4*)p = a0[i];
                *(float4*)(p + 4) = a1[i];
            }
        }
    } else {
        float* XC = wsf + XC_OFF;
        #pragma unroll
        for (int i = 0; i < 8; i++) {
            int r = rgrp + 16 * i;
            if (r < rows) {
                float* p = XC + (size_t)entp[r] * 128 + cgrp * 8;
                atomicAdd(p + 0, a0[i].x); atomicAdd(p + 1, a0[i].y);
                atomicAdd(p + 2, a0[i].z); atomicAdd(p + 3, a0[i].w);
                atomicAdd(p + 4, a1[i].x); atomicAdd(p + 5, a1[i].y);
                atomicAdd(p + 6, a1[i].z); atomicAdd(p + 7, a1[i].w);
            }
        }
    }
}

// XC[b,i,:] = sum of this (b,i)'s contiguous Y rows
__global__ __launch_bounds__(128) void k_reduce(unsigned* wsi, float* wsf) {
    int bi = blockIdx.x, tid = threadIdx.x;
    unsigned n = wsi[CNT_B + bi], off = wsi[OFF_B + bi];
    const float* Yp = wsf + Y_OFF + (size_t)off * 128 + tid;
    float a0 = 0.f, a1 = 0.f, a2 = 0.f, a3 = 0.f;
    unsigned e = 0;
    for (; e + 4 <= n; e += 4) {
        a0 += Yp[(size_t)e * 128];
        a1 += Yp[(size_t)(e + 1) * 128];
        a2 += Yp[(size_t)(e + 2) * 128];
        a3 += Yp[(size_t)(e + 3) * 128];
    }
    for (; e < n; e++) a0 += Yp[(size_t)e * 128];
    wsf[XC_OFF + (size_t)bi * 128 + tid] = (a0 + a1) + (a2 + a3);
}

// recurrence: h_new = sigmoid(XC[b,i] + h @ Wh); one block (256 thr) per batch b.
// Thread (col = tid>>1, khalf = tid&1) holds w[64] = Wh[khalf*64 .. +64)[col] in
// VGPRs (~88 total, no spill). K-halves combined with __shfl_xor(p,1) (adjacent
// lanes = same col). ONE barrier per step: reads of sh[cur] in iter i and writes
// of sh[cur] in iter i+1 are separated by the end-of-step barrier.
__global__ __launch_bounds__(256) void k_recur(const float* __restrict__ hw,
                                               const float* __restrict__ wsf,
                                               float* __restrict__ out) {
    int b = blockIdx.x;
    __shared__ float swh[16384];    // staging for weight transpose (used once)
    __shared__ float sh[2][128];
    int tid = threadIdx.x;
    int col = tid >> 1, khalf = tid & 1;
    int k0 = khalf * 64;

    const float4* hwg = (const float4*)hw;
    float4* swh4 = (float4*)swh;
    #pragma unroll
    for (int q = 0; q < 16; q++) swh4[q * 256 + tid] = hwg[q * 256 + tid];
    if (tid < 128) sh[0][tid] = 0.f;
    __syncthreads();
    float w[64];
    #pragma unroll
    for (int k = 0; k < 64; k++) w[k] = swh[(k0 + k) * 128 + col];

    const float* XC = wsf + XC_OFF + (size_t)b * 128 * 128;
    float xc_next = (khalf == 0) ? XC[col] : 0.f;   // row 0 prefetch
    int cur = 0;
    for (int i = 0; i < 128; i++) {
        float xc = xc_next;
        if (khalf == 0 && i < 127) xc_next = XC[(i + 1) * 128 + col];
        const float4* s4 = (const float4*)&sh[cur][k0];
        float acc0 = 0.f, acc1 = 0.f, acc2 = 0.f, acc3 = 0.f;
        #pragma unroll
        for (int kk = 0; kk < 16; kk++) {               // broadcast b128 reads
            float4 v = s4[kk];
            acc0 += v.x * w[4 * kk + 0];
            acc1 += v.y * w[4 * kk + 1];
            acc2 += v.z * w[4 * kk + 2];
            acc3 += v.w * w[4 * kk + 3];
        }
        float p = (acc0 + acc1) + (acc2 + acc3);
        p += __shfl_xor(p, 1);                          // combine K-halves in-wave
        if (khalf == 0) {
            float val = xc + p;
            val = 1.f / (1.f + __expf(-val));
            sh[cur ^ 1][col] = val;
            out[(size_t)(b * 128 + i) * 128 + col] = val;
        }
        cur ^= 1;
        __syncthreads();
    }
    if (tid < 128) out[(size_t)B_ * S_ * H_ + b * 128 + tid] = sh[cur][tid];
}

extern "C" void kernel_launch(void* const* d_in, const int* in_sizes, int n_in,
                              void* d_out, int out_size, void* d_ws, size_t ws_size,
                              hipStream_t stream) {
    const float* x  = (const float*)d_in[0];
    const int*   tc = (const int*)d_in[1];
    const int*   dc = (const int*)d_in[2];
    const int*   mk = (const int*)d_in[3];   // bool masks pushed as int32
    const float* tw = (const float*)d_in[4];
    const float* dw = (const float*)d_in[5];
    const float* hw = (const float*)d_in[6];
    float*    out = (float*)d_out;
    float*    wsf = (float*)d_ws;
    unsigned* wsi = (unsigned*)d_ws;
    char*     wsb = (char*)d_ws;

    int useY = (ws_size >= NEED_BYTES) ? 1 : 0;
    if (!useY)  // fallback path accumulates into XC with atomics -> needs zeroed XC
        hipMemsetAsync(wsb, 0, (size_t)262144 * 4, stream);

    k_hist1<<<dim3(256), dim3(256), 0, stream>>>(tc, dc, mk, wsi);
    k_scan_all<<<dim3(1), dim3(1024), 0, stream>>>(wsi);
    k_scatter<<<dim3(256), dim3(256), 0, stream>>>(tc, dc, mk, wsi, useY);
    k_phaseA<<<dim3(NS, 16), dim3(256), 0, stream>>>(x, tw, wsi, wsf);
    k_phaseB<<<dim3(NS, 16), dim3(256), 0, stream>>>(dw, wsi, wsf, useY);
    if (useY) k_reduce<<<dim3(2048), dim3(128), 0, stream>>>(wsi, wsf);
    k_recur<<<dim3(16), dim3(256), 0, stream>>>(hw, wsf, out);
}